// Round 9
// baseline (878.362 us; speedup 1.0000x reference)
//
#include <hip/hip_runtime.h>
#include <hip/hip_cooperative_groups.h>
#include <hip/hip_bf16.h>
#include <type_traits>
#include <utility>

// Problem: B=32, P=4, N=1024, C=384.
// softmax over a size-1 axis == 1.0, so:
//   cv[b,p,:]  = (sum_n x[b,p,n,:]) @ Wk + N*bk          (fp32, exact)
//   out        = (relu(x@Wv + bv) * cv) @ Wp + bp        (bf16 MFMA)
// Primary: ONE cooperative kernel (x read once):
//   phase1: x -> bf16 swizzled tile images in ws (block-local) + column sums
//   phase2: cv
//   phase3: per-block 8-tile loop, global_load_lds identity staging (dbuf),
//           GEMM1 -> relu*cv -> GEMM2 -> out
// Fallback (coop refused / small ws): r5 path (k_xsum + k_cv + k_fused).
#define C_     384
#define N_     1024
#define G_     128
#define QKVD   769
#define NBLK   512
#define TILE_B 24576      // 32 rows x 384 bf16

namespace cg = cooperative_groups;

typedef float  f32x4 __attribute__((ext_vector_type(4)));
typedef short  s16x8 __attribute__((ext_vector_type(8)));
typedef __bf16 b16x8 __attribute__((ext_vector_type(8)));

template <typename V, typename = void>
struct mfma_takes : std::false_type {};
template <typename V>
struct mfma_takes<V, std::void_t<decltype(__builtin_amdgcn_mfma_f32_16x16x32_bf16(
    std::declval<V>(), std::declval<V>(), std::declval<f32x4>(), 0, 0, 0))>>
    : std::true_type {};

using frag_t = std::conditional_t<mfma_takes<s16x8>::value, s16x8, b16x8>;

template <typename V>
__device__ __forceinline__ f32x4 mfma_bf16(V a, V b, f32x4 c) {
  return __builtin_amdgcn_mfma_f32_16x16x32_bf16(a, b, c, 0, 0, 0);
}

__device__ __forceinline__ unsigned short f2bf(float f) {
  union { float f; unsigned u; } v; v.f = f;
  unsigned r = v.u + 0x7fffu + ((v.u >> 16) & 1u);   // RNE
  return (unsigned short)(r >> 16);
}
__device__ __forceinline__ unsigned pack2(float lo, float hi) {
  return (unsigned)f2bf(lo) | ((unsigned)f2bf(hi) << 16);
}

// async global->LDS 16B: uniform LDS base, HW adds lane*16; global addr per-lane
__device__ __forceinline__ void stage16(const char* g, char* lbase, int lane) {
#if __has_builtin(__builtin_amdgcn_global_load_lds)
  __builtin_amdgcn_global_load_lds(
      (const __attribute__((address_space(1))) void*)g,
      (__attribute__((address_space(3))) void*)lbase, 16, 0, 0);
#else
  *(uint4*)(lbase + lane * 16) = *(const uint4*)g;
#endif
}

// ------- pack Wv (w_qkv[:,385:769]) and Wp (w_proj) as bf16 frag-major -------
__global__ void k_pack(const float* __restrict__ w_qkv, const float* __restrict__ w_proj,
                       unsigned short* __restrict__ pWv, unsigned short* __restrict__ pWp) {
  int bid = blockIdx.x;
  int mat = bid / 288;
  int r   = bid % 288;
  int kk = r / 24, nf = r % 24;
  int lane = threadIdx.x;
  int kbase = kk * 32 + (lane >> 4) * 8;
  int n = nf * 16 + (lane & 15);
  unsigned v[4];
#pragma unroll
  for (int jj = 0; jj < 4; ++jj) {
    int k0 = kbase + jj * 2;
    float f0 = mat ? w_proj[(size_t)k0 * C_ + n]       : w_qkv[(size_t)k0 * QKVD + 385 + n];
    float f1 = mat ? w_proj[(size_t)(k0 + 1) * C_ + n] : w_qkv[(size_t)(k0 + 1) * QKVD + 385 + n];
    v[jj] = (unsigned)f2bf(f0) | ((unsigned)f2bf(f1) << 16);
  }
  unsigned short* dst = (mat ? pWp : pWv) + ((size_t)r * 64 + lane) * 8;
  uint4 w; w.x = v[0]; w.y = v[1]; w.z = v[2]; w.w = v[3];
  *(uint4*)dst = w;
}

// ================= cooperative all-in-one =================
__global__ __launch_bounds__(512, 4) void k_coop(
    const float* __restrict__ x, const float* __restrict__ w_qkv,
    const float* __restrict__ b_qkv, const float* __restrict__ b_proj,
    const unsigned short* __restrict__ pWv, const unsigned short* __restrict__ pWp,
    float* __restrict__ xsum, float* __restrict__ cvp,
    char* __restrict__ xbb, float* __restrict__ out) {
  __shared__ __align__(16) char buf[2][TILE_B];
  __shared__ float xs[C_];

  const int tid  = threadIdx.x;
  const int lane = tid & 63;
  const int wv   = tid >> 6;          // 0..7
  const int b    = blockIdx.x;        // 512 blocks; block owns rows [b*256, b*256+256)
  const int g    = b >> 2;            // group (1024 rows per group, 4 blocks each)

  // ---------------- phase 1: x -> bf16 swizzled images + column sums ----------------
  if (tid < 384) {
    const int col8 = (tid % 48) * 8;
    const int rgrp = tid / 48;        // 0..7 -> rows rgrp*4..+4 of each 32-row tile
    float s0=0,s1=0,s2=0,s3=0,s4=0,s5=0,s6=0,s7=0;
    for (int t = 0; t < 8; ++t) {
      const float* xt = x + ((size_t)b * 256 + (size_t)t * 32) * C_;
      char* img = xbb + (size_t)(b * 8 + t) * TILE_B;
#pragma unroll
      for (int jj = 0; jj < 4; ++jj) {
        int row = rgrp * 4 + jj;
        float4 a = *(const float4*)(xt + (size_t)row * C_ + col8);
        float4 c = *(const float4*)(xt + (size_t)row * C_ + col8 + 4);
        uint4 w;
        w.x = pack2(a.x, a.y); w.y = pack2(a.z, a.w);
        w.z = pack2(c.x, c.y); w.w = pack2(c.z, c.w);
        *(uint4*)(img + ((row * 768 + col8 * 2) ^ ((row & 7) << 4))) = w;
        s0 += a.x; s1 += a.y; s2 += a.z; s3 += a.w;
        s4 += c.x; s5 += c.y; s6 += c.z; s7 += c.w;
      }
    }
    atomicAdd(&xsum[g * C_ + col8 + 0], s0);
    atomicAdd(&xsum[g * C_ + col8 + 1], s1);
    atomicAdd(&xsum[g * C_ + col8 + 2], s2);
    atomicAdd(&xsum[g * C_ + col8 + 3], s3);
    atomicAdd(&xsum[g * C_ + col8 + 4], s4);
    atomicAdd(&xsum[g * C_ + col8 + 5], s5);
    atomicAdd(&xsum[g * C_ + col8 + 6], s6);
    atomicAdd(&xsum[g * C_ + col8 + 7], s7);
  }

  cg::this_grid().sync();

  // ---------------- phase 2: cv[g][c] (block b does group b>>2, quarter b&3) ----------------
  if (tid < C_) xs[tid] = xsum[g * C_ + tid];
  __syncthreads();
  if (tid < 96) {
    int c = (b & 3) * 96 + tid;
    float acc = 0.f;
#pragma unroll 4
    for (int k = 0; k < C_; ++k) acc += xs[k] * w_qkv[k * QKVD + 1 + c];
    cvp[g * C_ + c] = acc + (float)N_ * b_qkv[1 + c];
  }

  cg::this_grid().sync();

  // ---------------- phase 3: pipelined 8-tile fused GEMMs ----------------
  // wave wv: all 32 rows x cols [wv*48, wv*48+48)
  float cvr[3], bvr[3], bpr[3];
#pragma unroll
  for (int n = 0; n < 3; ++n) {
    int col = wv * 48 + n * 16 + (lane & 15);
    cvr[n] = cvp[g * C_ + col];
    bvr[n] = b_qkv[1 + C_ + col];
    bpr[n] = b_proj[col];
  }

  const char* myxb = xbb + (size_t)b * 8 * TILE_B;
  const f32x4 zero = {0.f, 0.f, 0.f, 0.f};

  // prologue: stage tile 0
#pragma unroll
  for (int j = 0; j < 3; ++j) {
    int cb = (wv * 3 + j) * 1024;
    stage16(myxb + cb + lane * 16, (char*)buf[0] + cb, lane);
  }
  __syncthreads();

#pragma unroll 1
  for (int t = 0; t < 8; ++t) {
    const int p = t & 1;

    // prefetch next tile into the other buffer (lands by the next barrier)
    if (t < 7) {
      const char* src = myxb + (size_t)(t + 1) * TILE_B;
#pragma unroll
      for (int j = 0; j < 3; ++j) {
        int cb = (wv * 3 + j) * 1024;
        stage16(src + cb + lane * 16, (char*)buf[p ^ 1] + cb, lane);
      }
    }

    // ---- GEMM1: value = x @ Wv ----
    f32x4 acc[2][3];
#pragma unroll
    for (int m = 0; m < 2; ++m)
#pragma unroll
      for (int n = 0; n < 3; ++n) acc[m][n] = zero;

    for (int kk = 0; kk < 12; ++kk) {
      frag_t A[2], Bv[3];
      int kb2 = (kk * 32 + (lane >> 4) * 8) * 2;
#pragma unroll
      for (int m = 0; m < 2; ++m) {
        int row = m * 16 + (lane & 15);
        A[m] = *(const frag_t*)(buf[p] + ((row * 768 + kb2) ^ ((row & 7) << 4)));
      }
      const unsigned short* bp_ = pWv + ((size_t)(kk * 24 + wv * 3) * 64 + lane) * 8;
#pragma unroll
      for (int n = 0; n < 3; ++n) Bv[n] = *(const frag_t*)(bp_ + (size_t)n * 64 * 8);
#pragma unroll
      for (int m = 0; m < 2; ++m)
#pragma unroll
        for (int n = 0; n < 3; ++n) acc[m][n] = mfma_bf16(A[m], Bv[n], acc[m][n]);
    }
    __syncthreads();   // all waves done reading buf[p]; prefetch also drained

    // ---- epilogue1: gated = relu(value + bv) * cv -> bf16 -> buf[p] in place ----
#pragma unroll
    for (int m = 0; m < 2; ++m) {
#pragma unroll
      for (int n = 0; n < 3; ++n) {
        int col = wv * 48 + n * 16 + (lane & 15);
#pragma unroll
        for (int r = 0; r < 4; ++r) {
          int row = m * 16 + (lane >> 4) * 4 + r;   // verified C/D layout
          float val = fmaxf(acc[m][n][r] + bvr[n], 0.f) * cvr[n];
          *(unsigned short*)(buf[p] + ((row * 768 + col * 2) ^ ((row & 7) << 4))) = f2bf(val);
        }
      }
    }
    __syncthreads();

    // ---- GEMM2: out = gated @ Wp ----
#pragma unroll
    for (int m = 0; m < 2; ++m)
#pragma unroll
      for (int n = 0; n < 3; ++n) acc[m][n] = zero;

    for (int kk = 0; kk < 12; ++kk) {
      frag_t A[2], Bv[3];
      int kb2 = (kk * 32 + (lane >> 4) * 8) * 2;
#pragma unroll
      for (int m = 0; m < 2; ++m) {
        int row = m * 16 + (lane & 15);
        A[m] = *(const frag_t*)(buf[p] + ((row * 768 + kb2) ^ ((row & 7) << 4)));
      }
      const unsigned short* bp_ = pWp + ((size_t)(kk * 24 + wv * 3) * 64 + lane) * 8;
#pragma unroll
      for (int n = 0; n < 3; ++n) Bv[n] = *(const frag_t*)(bp_ + (size_t)n * 64 * 8);
#pragma unroll
      for (int m = 0; m < 2; ++m)
#pragma unroll
        for (int n = 0; n < 3; ++n) acc[m][n] = mfma_bf16(A[m], Bv[n], acc[m][n]);
    }

    // ---- epilogue2: out = acc + bp ----
#pragma unroll
    for (int m = 0; m < 2; ++m) {
#pragma unroll
      for (int n = 0; n < 3; ++n) {
        int col = wv * 48 + n * 16 + (lane & 15);
#pragma unroll
        for (int r = 0; r < 4; ++r) {
          int row = m * 16 + (lane >> 4) * 4 + r;
          out[((size_t)b * 256 + (size_t)t * 32 + row) * C_ + col] = acc[m][n][r] + bpr[n];
        }
      }
    }
    __syncthreads();   // buf[p] free for reuse; prefetched buf[p^1] ready
  }
}

// ================= fallback path (r5, proven 229us) =================
__global__ __launch_bounds__(384) void k_xsum(const float* __restrict__ x,
                                              float* __restrict__ xsum) {
  __shared__ float sh[4][C_];
  const int tid = threadIdx.x;
  const int c4  = (tid % 96) * 4;
  const int rg  = tid / 96;
  const int b   = blockIdx.x;
  const int g   = b >> 3;
  const float* p = x + ((size_t)b * 128 + (size_t)rg * 32) * C_ + c4;
  f32x4 s = {0.f, 0.f, 0.f, 0.f};
#pragma unroll 8
  for (int r = 0; r < 32; ++r) {
    float4 v = *(const float4*)(p + (size_t)r * C_);
    s.x += v.x; s.y += v.y; s.z += v.z; s.w += v.w;
  }
  *(f32x4*)&sh[rg][c4] = s;
  __syncthreads();
  if (rg == 0) {
#pragma unroll
    for (int j = 0; j < 4; ++j) {
      float v = sh[0][c4 + j] + sh[1][c4 + j] + sh[2][c4 + j] + sh[3][c4 + j];
      atomicAdd(&xsum[g * C_ + c4 + j], v);
    }
  }
}

__global__ void k_cv(const float* __restrict__ xsum, const float* __restrict__ w_qkv,
                     const float* __restrict__ b_qkv, float* __restrict__ cv) {
  __shared__ float xs[C_];
  int g = blockIdx.x, c = threadIdx.x;
  xs[c] = xsum[g * C_ + c];
  __syncthreads();
  float acc = 0.f;
#pragma unroll 4
  for (int k = 0; k < C_; ++k) acc += xs[k] * w_qkv[k * QKVD + 1 + c];
  cv[g * C_ + c] = acc + (float)N_ * b_qkv[1 + c];
}

__global__ __launch_bounds__(256) void k_fused(
    const float* __restrict__ x, const unsigned short* __restrict__ pWv,
    const unsigned short* __restrict__ pWp, const float* __restrict__ cv,
    const float* __restrict__ b_qkv, const float* __restrict__ b_proj,
    float* __restrict__ out) {
  __shared__ __align__(16) char tile[32 * 768];
  __shared__ float cv_l[C_], bv_l[C_], bp_l[C_];

  const int tid  = threadIdx.x;
  const int lane = tid & 63;
  const int wv   = tid >> 6;
  const int R0   = blockIdx.x * 32;
  const int g    = R0 >> 10;

  for (int c = tid; c < C_; c += 256) {
    cv_l[c] = cv[g * C_ + c];
    bv_l[c] = b_qkv[1 + C_ + c];
    bp_l[c] = b_proj[c];
  }
  {
    const float* xg = x + (size_t)R0 * C_;
#pragma unroll
    for (int j = 0; j < 6; ++j) {
      int ch  = tid + j * 256;
      int row = ch / 48;
      int c8  = (ch % 48) * 8;
      const float4* s0 = (const float4*)(xg + (size_t)row * C_ + c8);
      float4 a = s0[0], b = s0[1];
      uint4 w;
      w.x = pack2(a.x, a.y); w.y = pack2(a.z, a.w);
      w.z = pack2(b.x, b.y); w.w = pack2(b.z, b.w);
      int byte = (row * 768 + c8 * 2) ^ ((row & 7) << 4);
      *(uint4*)(tile + byte) = w;
    }
  }
  __syncthreads();

  const f32x4 zero = {0.f, 0.f, 0.f, 0.f};
  f32x4 acc[2][6];
#pragma unroll
  for (int m = 0; m < 2; ++m)
#pragma unroll
    for (int n = 0; n < 6; ++n) acc[m][n] = zero;

  for (int kk = 0; kk < 12; ++kk) {
    frag_t A[2], Bv[6];
    int kb2 = (kk * 32 + (lane >> 4) * 8) * 2;
#pragma unroll
    for (int m = 0; m < 2; ++m) {
      int row = m * 16 + (lane & 15);
      A[m] = *(const frag_t*)(tile + ((row * 768 + kb2) ^ ((row & 7) << 4)));
    }
    const unsigned short* bp_ = pWv + ((size_t)(kk * 24 + wv * 6) * 64 + lane) * 8;
#pragma unroll
    for (int n = 0; n < 6; ++n) Bv[n] = *(const frag_t*)(bp_ + (size_t)n * 64 * 8);
#pragma unroll
    for (int m = 0; m < 2; ++m)
#pragma unroll
      for (int n = 0; n < 6; ++n) acc[m][n] = mfma_bf16(A[m], Bv[n], acc[m][n]);
  }
  __syncthreads();

#pragma unroll
  for (int m = 0; m < 2; ++m) {
#pragma unroll
    for (int n = 0; n < 6; ++n) {
      int col = wv * 96 + n * 16 + (lane & 15);
      float cvv = cv_l[col], bvv = bv_l[col];
#pragma unroll
      for (int r = 0; r < 4; ++r) {
        int row = m * 16 + (lane >> 4) * 4 + r;
        float val = fmaxf(acc[m][n][r] + bvv, 0.f) * cvv;
        *(unsigned short*)(tile + ((row * 768 + col * 2) ^ ((row & 7) << 4))) = f2bf(val);
      }
    }
  }
  __syncthreads();

#pragma unroll
  for (int m = 0; m < 2; ++m)
#pragma unroll
    for (int n = 0; n < 6; ++n) acc[m][n] = zero;

  for (int kk = 0; kk < 12; ++kk) {
    frag_t A[2], Bv[6];
    int kb2 = (kk * 32 + (lane >> 4) * 8) * 2;
#pragma unroll
    for (int m = 0; m < 2; ++m) {
      int row = m * 16 + (lane & 15);
      A[m] = *(const frag_t*)(tile + ((row * 768 + kb2) ^ ((row & 7) << 4)));
    }
    const unsigned short* bp_ = pWp + ((size_t)(kk * 24 + wv * 6) * 64 + lane) * 8;
#pragma unroll
    for (int n = 0; n < 6; ++n) Bv[n] = *(const frag_t*)(bp_ + (size_t)n * 64 * 8);
#pragma unroll
    for (int m = 0; m < 2; ++m)
#pragma unroll
      for (int n = 0; n < 6; ++n) acc[m][n] = mfma_bf16(A[m], Bv[n], acc[m][n]);
  }

#pragma unroll
  for (int m = 0; m < 2; ++m) {
#pragma unroll
    for (int n = 0; n < 6; ++n) {
      int col = wv * 96 + n * 16 + (lane & 15);
      float bpv = bp_l[col];
#pragma unroll
      for (int r = 0; r < 4; ++r) {
        int row = m * 16 + (lane >> 4) * 4 + r;
        out[(size_t)(R0 + row) * C_ + col] = acc[m][n][r] + bpv;
      }
    }
  }
}

extern "C" void kernel_launch(void* const* d_in, const int* in_sizes, int n_in,
                              void* d_out, int out_size, void* d_ws, size_t ws_size,
                              hipStream_t stream) {
  const float* x      = (const float*)d_in[0];
  const float* w_qkv  = (const float*)d_in[1];
  const float* b_qkv  = (const float*)d_in[2];
  const float* w_proj = (const float*)d_in[3];
  const float* b_proj = (const float*)d_in[4];
  float* out = (float*)d_out;

  // ws: xsum | cv | pWv | pWp | xb (swizzled bf16 tile images, ~100.7 MB)
  float* xsum = (float*)d_ws;
  float* cvp  = xsum + G_ * C_;
  unsigned short* pWv = (unsigned short*)(cvp + G_ * C_);
  unsigned short* pWp = pWv + C_ * C_;
  char* xbb = (char*)(pWp + C_ * C_);

  const size_t need = 983040 + (size_t)NBLK * 8 * TILE_B;   // ~101.6 MB

  hipMemsetAsync(xsum, 0, G_ * C_ * sizeof(float), stream);
  k_pack<<<576, 64, 0, stream>>>(w_qkv, w_proj, pWv, pWp);

  bool coop_ok = false;
  if (ws_size >= need) {
    void* args[10] = {(void*)&x, (void*)&w_qkv, (void*)&b_qkv, (void*)&b_proj,
                      (void*)&pWv, (void*)&pWp, (void*)&xsum, (void*)&cvp,
                      (void*)&xbb, (void*)&out};
    hipError_t e = hipLaunchCooperativeKernel((const void*)k_coop, dim3(NBLK),
                                              dim3(512), args, 0, stream);
    coop_ok = (e == hipSuccess);
  }
  if (!coop_ok) {
    k_xsum<<<1024, 384, 0, stream>>>(x, xsum);
    k_cv<<<G_, C_, 0, stream>>>(xsum, w_qkv, b_qkv, cvp);
    k_fused<<<4096, 256, 0, stream>>>(x, pWv, pWp, cvp, b_qkv, b_proj, out);
  }
}

// Round 10
// 234.304 us; speedup vs baseline: 3.7488x; 3.7488x over previous
//
#include <hip/hip_runtime.h>
#include <hip/hip_bf16.h>
#include <type_traits>
#include <utility>

// Problem: B=32, P=4, N=1024, C=384.
// softmax over a size-1 axis == 1.0, so:
//   cv[b,p,:]  = (sum_n x[b,p,n,:]) @ Wk + N*bk          (fp32, exact)
//   out        = (relu(x@Wv + bv) * cv) @ Wp + bp        (bf16 MFMA, fused)
#define C_    384
#define N_    1024
#define G_    128          // B*P groups
#define QKVD  769

typedef float  f32x4 __attribute__((ext_vector_type(4)));
typedef short  s16x8 __attribute__((ext_vector_type(8)));
typedef __bf16 b16x8 __attribute__((ext_vector_type(8)));

template <typename V, typename = void>
struct mfma_takes : std::false_type {};
template <typename V>
struct mfma_takes<V, std::void_t<decltype(__builtin_amdgcn_mfma_f32_16x16x32_bf16(
    std::declval<V>(), std::declval<V>(), std::declval<f32x4>(), 0, 0, 0))>>
    : std::true_type {};

using frag_t = std::conditional_t<mfma_takes<s16x8>::value, s16x8, b16x8>;

template <typename V>
__device__ __forceinline__ f32x4 mfma_bf16(V a, V b, f32x4 c) {
  return __builtin_amdgcn_mfma_f32_16x16x32_bf16(a, b, c, 0, 0, 0);
}

__device__ __forceinline__ unsigned short f2bf(float f) {
  union { float f; unsigned u; } v; v.f = f;
  unsigned r = v.u + 0x7fffu + ((v.u >> 16) & 1u);   // RNE
  return (unsigned short)(r >> 16);
}
__device__ __forceinline__ unsigned pack2(float lo, float hi) {
  return (unsigned)f2bf(lo) | ((unsigned)f2bf(hi) << 16);
}

// ---------------- K1: xsum[g][c] = sum_n x[g][n][c]  (float4, LDS-reduced) ----------------
__global__ __launch_bounds__(384) void k_xsum(const float* __restrict__ x,
                                              float* __restrict__ xsum) {
  __shared__ float sh[4][C_];
  const int tid = threadIdx.x;
  const int c4  = (tid % 96) * 4;
  const int rg  = tid / 96;            // 0..3
  const int b   = blockIdx.x;          // 1024
  const int g   = b >> 3;
  const float* p = x + ((size_t)b * 128 + (size_t)rg * 32) * C_ + c4;
  f32x4 s = {0.f, 0.f, 0.f, 0.f};
#pragma unroll 8
  for (int r = 0; r < 32; ++r) {
    float4 v = *(const float4*)(p + (size_t)r * C_);
    s.x += v.x; s.y += v.y; s.z += v.z; s.w += v.w;
  }
  *(f32x4*)&sh[rg][c4] = s;
  __syncthreads();
  if (rg == 0) {
#pragma unroll
    for (int j = 0; j < 4; ++j) {
      float v = sh[0][c4 + j] + sh[1][c4 + j] + sh[2][c4 + j] + sh[3][c4 + j];
      atomicAdd(&xsum[g * C_ + c4 + j], v);
    }
  }
}

// ---------------- K2: cv[g][c] = xsum[g]@Wk[:,c] + N*bk[c] ----------------
__global__ void k_cv(const float* __restrict__ xsum, const float* __restrict__ w_qkv,
                     const float* __restrict__ b_qkv, float* __restrict__ cv) {
  __shared__ float xs[C_];
  int g = blockIdx.x, c = threadIdx.x;   // 384 threads
  xs[c] = xsum[g * C_ + c];
  __syncthreads();
  float acc = 0.f;
#pragma unroll 4
  for (int k = 0; k < C_; ++k) acc += xs[k] * w_qkv[k * QKVD + 1 + c];
  cv[g * C_ + c] = acc + (float)N_ * b_qkv[1 + c];
}

// ------- K3: pack Wv (w_qkv[:,385:769]) and Wp (w_proj) as bf16 frag-major -------
// entry (kk,nf,lane) -> 8 bf16 = B[k = kk*32+(lane>>4)*8 + j][n = nf*16+(lane&15)]
__global__ void k_pack(const float* __restrict__ w_qkv, const float* __restrict__ w_proj,
                       unsigned short* __restrict__ pWv, unsigned short* __restrict__ pWp) {
  int bid = blockIdx.x;
  int mat = bid / 288;             // 0: Wv, 1: Wp    (288 = 12 kk * 24 nf)
  int r   = bid % 288;
  int kk = r / 24, nf = r % 24;
  int lane = threadIdx.x;          // 64
  int kbase = kk * 32 + (lane >> 4) * 8;
  int n = nf * 16 + (lane & 15);
  unsigned v[4];
#pragma unroll
  for (int jj = 0; jj < 4; ++jj) {
    int k0 = kbase + jj * 2;
    float f0 = mat ? w_proj[(size_t)k0 * C_ + n]       : w_qkv[(size_t)k0 * QKVD + 385 + n];
    float f1 = mat ? w_proj[(size_t)(k0 + 1) * C_ + n] : w_qkv[(size_t)(k0 + 1) * QKVD + 385 + n];
    v[jj] = (unsigned)f2bf(f0) | ((unsigned)f2bf(f1) << 16);
  }
  unsigned short* dst = (mat ? pWp : pWv) + ((size_t)r * 64 + lane) * 8;
  uint4 w; w.x = v[0]; w.y = v[1]; w.z = v[2]; w.w = v[3];
  *(uint4*)dst = w;
}

// ---------------- K4: fused value-GEMM -> relu*cv -> proj-GEMM ----------------
// 4096 blocks x 512 thr (8 waves). Block = 32 rows x 384 cols.
// Wave w: all 32 rows x cols [w*48, w*48+48) -> acc[2][3] = 24 VGPR. Target:
// total VGPR <= 64 (occupancy cliff at 64 -> up to 32 waves/CU). All register
// indices compile-time (rule #20). NO min-occupancy launch_bounds arg (r3/r9!).
__global__ __launch_bounds__(512) void k_fused(
    const float* __restrict__ x, const unsigned short* __restrict__ pWv,
    const unsigned short* __restrict__ pWp, const float* __restrict__ cv,
    const float* __restrict__ b_qkv, const float* __restrict__ b_proj,
    float* __restrict__ out) {
  __shared__ __align__(16) char tile[32 * 768];   // 32 rows x 384 bf16, XOR-swizzled
  __shared__ float cv_l[C_], bv_l[C_], bp_l[C_];

  const int tid  = threadIdx.x;
  const int lane = tid & 63;
  const int wv   = tid >> 6;                 // 0..7
  const int R0   = blockIdx.x * 32;
  const int g    = R0 >> 10;

  if (tid < C_) {
    cv_l[tid] = cv[g * C_ + tid];
    bv_l[tid] = b_qkv[1 + C_ + tid];
    bp_l[tid] = b_proj[tid];
  }

  // stage 32x384 fp32 -> bf16 -> LDS (swizzle: byte off ^= (row&7)<<4)
  {
    const float* xg = x + (size_t)R0 * C_;
#pragma unroll
    for (int j = 0; j < 3; ++j) {
      int ch  = tid + j * 512;          // 1536 chunks of 8 f32
      int row = ch / 48;
      int c8  = (ch % 48) * 8;          // element col
      const float4* s0 = (const float4*)(xg + (size_t)row * C_ + c8);
      float4 a = s0[0], b = s0[1];
      uint4 w;
      w.x = pack2(a.x, a.y); w.y = pack2(a.z, a.w);
      w.z = pack2(b.x, b.y); w.w = pack2(b.z, b.w);
      int byte = (row * 768 + c8 * 2) ^ ((row & 7) << 4);
      *(uint4*)(tile + byte) = w;
    }
  }
  __syncthreads();

  const f32x4 zero = {0.f, 0.f, 0.f, 0.f};
  f32x4 acc[2][3];
#pragma unroll
  for (int m = 0; m < 2; ++m)
#pragma unroll
    for (int n = 0; n < 3; ++n) acc[m][n] = zero;

  // ---- GEMM1: value = x @ Wv ----
  for (int kk = 0; kk < 12; ++kk) {
    frag_t A[2], Bv[3];
    int kb2 = (kk * 32 + (lane >> 4) * 8) * 2;
#pragma unroll
    for (int m = 0; m < 2; ++m) {
      int row = m * 16 + (lane & 15);
      A[m] = *(const frag_t*)(tile + ((row * 768 + kb2) ^ ((row & 7) << 4)));
    }
    const unsigned short* bp_ = pWv + ((size_t)(kk * 24 + wv * 3) * 64 + lane) * 8;
#pragma unroll
    for (int n = 0; n < 3; ++n) Bv[n] = *(const frag_t*)(bp_ + (size_t)n * 64 * 8);
#pragma unroll
    for (int m = 0; m < 2; ++m)
#pragma unroll
      for (int n = 0; n < 3; ++n) acc[m][n] = mfma_bf16(A[m], Bv[n], acc[m][n]);
  }
  __syncthreads();   // all waves done reading x tile

  // ---- epilogue1: gated = relu(value + bv) * cv -> bf16 -> same LDS tile ----
#pragma unroll
  for (int m = 0; m < 2; ++m) {
#pragma unroll
    for (int n = 0; n < 3; ++n) {
      int col = wv * 48 + n * 16 + (lane & 15);
      float cvv = cv_l[col], bvv = bv_l[col];
#pragma unroll
      for (int r = 0; r < 4; ++r) {
        int row = m * 16 + (lane >> 4) * 4 + r;   // verified C/D layout
        float val = fmaxf(acc[m][n][r] + bvv, 0.f) * cvv;
        *(unsigned short*)(tile + ((row * 768 + col * 2) ^ ((row & 7) << 4))) = f2bf(val);
      }
    }
  }
  __syncthreads();   // gated tile complete

  // ---- GEMM2: out = gated @ Wp ----
#pragma unroll
  for (int m = 0; m < 2; ++m)
#pragma unroll
    for (int n = 0; n < 3; ++n) acc[m][n] = zero;

  for (int kk = 0; kk < 12; ++kk) {
    frag_t A[2], Bv[3];
    int kb2 = (kk * 32 + (lane >> 4) * 8) * 2;
#pragma unroll
    for (int m = 0; m < 2; ++m) {
      int row = m * 16 + (lane & 15);
      A[m] = *(const frag_t*)(tile + ((row * 768 + kb2) ^ ((row & 7) << 4)));
    }
    const unsigned short* bp_ = pWp + ((size_t)(kk * 24 + wv * 3) * 64 + lane) * 8;
#pragma unroll
    for (int n = 0; n < 3; ++n) Bv[n] = *(const frag_t*)(bp_ + (size_t)n * 64 * 8);
#pragma unroll
    for (int m = 0; m < 2; ++m)
#pragma unroll
      for (int n = 0; n < 3; ++n) acc[m][n] = mfma_bf16(A[m], Bv[n], acc[m][n]);
  }

  // ---- epilogue2: out = acc + bp ----
#pragma unroll
  for (int m = 0; m < 2; ++m) {
#pragma unroll
    for (int n = 0; n < 3; ++n) {
      int col = wv * 48 + n * 16 + (lane & 15);
      float bpv = bp_l[col];
#pragma unroll
      for (int r = 0; r < 4; ++r) {
        int row = m * 16 + (lane >> 4) * 4 + r;
        out[(size_t)(R0 + row) * C_ + col] = acc[m][n][r] + bpv;
      }
    }
  }
}

extern "C" void kernel_launch(void* const* d_in, const int* in_sizes, int n_in,
                              void* d_out, int out_size, void* d_ws, size_t ws_size,
                              hipStream_t stream) {
  const float* x      = (const float*)d_in[0];
  const float* w_qkv  = (const float*)d_in[1];
  const float* b_qkv  = (const float*)d_in[2];
  const float* w_proj = (const float*)d_in[3];
  const float* b_proj = (const float*)d_in[4];
  float* out = (float*)d_out;

  // ws: xsum[128*384 f] | cv[128*384 f] | pWv[147456 bf16] | pWp[147456 bf16]  (~1 MB)
  float* xsum = (float*)d_ws;
  float* cvp  = xsum + G_ * C_;
  unsigned short* pWv = (unsigned short*)(cvp + G_ * C_);
  unsigned short* pWp = pWv + C_ * C_;

  hipMemsetAsync(xsum, 0, G_ * C_ * sizeof(float), stream);
  k_xsum<<<1024, 384, 0, stream>>>(x, xsum);        // also warms L3 with x
  k_pack<<<576, 64, 0, stream>>>(w_qkv, w_proj, pWv, pWp);
  k_cv<<<G_, C_, 0, stream>>>(xsum, w_qkv, b_qkv, cvp);
  k_fused<<<4096, 512, 0, stream>>>(x, pWv, pWp, cvp, b_qkv, b_proj, out);
}

// Round 11
// 233.135 us; speedup vs baseline: 3.7676x; 1.0050x over previous
//
#include <hip/hip_runtime.h>
#include <hip/hip_bf16.h>
#include <type_traits>
#include <utility>

// Problem: B=32, P=4, N=1024, C=384.
// softmax over a size-1 axis == 1.0, so:
//   cv[b,p,:]  = (sum_n x[b,p,n,:]) @ Wk + N*bk          (fp32, exact)
//   out        = (relu(x@Wv + bv) * cv) @ Wp + bp        (bf16 MFMA, fused)
// Pipeline: k_prep (x -> swizzled bf16 tile images + xsum) ; k_cv ; k_pack ;
//           k_fused (identity global_load_lds stage -> GEMM1 -> relu*cv -> GEMM2)
#define C_     384
#define N_     1024
#define G_     128         // B*P groups
#define QKVD   769
#define TILE_B 24576       // one 32-row x 384-col bf16 tile image

typedef float  f32x4 __attribute__((ext_vector_type(4)));
typedef short  s16x8 __attribute__((ext_vector_type(8)));
typedef __bf16 b16x8 __attribute__((ext_vector_type(8)));

template <typename V, typename = void>
struct mfma_takes : std::false_type {};
template <typename V>
struct mfma_takes<V, std::void_t<decltype(__builtin_amdgcn_mfma_f32_16x16x32_bf16(
    std::declval<V>(), std::declval<V>(), std::declval<f32x4>(), 0, 0, 0))>>
    : std::true_type {};

using frag_t = std::conditional_t<mfma_takes<s16x8>::value, s16x8, b16x8>;

template <typename V>
__device__ __forceinline__ f32x4 mfma_bf16(V a, V b, f32x4 c) {
  return __builtin_amdgcn_mfma_f32_16x16x32_bf16(a, b, c, 0, 0, 0);
}

__device__ __forceinline__ unsigned short f2bf(float f) {
  union { float f; unsigned u; } v; v.f = f;
  unsigned r = v.u + 0x7fffu + ((v.u >> 16) & 1u);   // RNE
  return (unsigned short)(r >> 16);
}
__device__ __forceinline__ unsigned pack2(float lo, float hi) {
  return (unsigned)f2bf(lo) | ((unsigned)f2bf(hi) << 16);
}

// async global->LDS 16B: uniform LDS base, HW adds lane*16
__device__ __forceinline__ void stage16(const char* g, char* lbase, int lane) {
#if __has_builtin(__builtin_amdgcn_global_load_lds)
  __builtin_amdgcn_global_load_lds(
      (const __attribute__((address_space(1))) void*)g,
      (__attribute__((address_space(3))) void*)lbase, 16, 0, 0);
#else
  *(uint4*)(lbase + lane * 16) = *(const uint4*)g;
#endif
}

// ---------------- K_prep: x -> swizzled bf16 tile images + xsum ----------------
// 2048 blocks x 384 thr; block = 64 rows = 2 tile images. Thread: 8 rows x 8 cols.
__global__ __launch_bounds__(384) void k_prep(const float* __restrict__ x,
                                              char* __restrict__ xbb,
                                              float* __restrict__ xsum) {
  __shared__ float csum[C_];
  const int b    = blockIdx.x;        // 2048
  const int g    = b >> 4;            // 16 blocks per group
  const int tid  = threadIdx.x;       // 384
  const int col8 = (tid % 48) * 8;
  const int rg   = tid / 48;          // 0..7 -> 8 rows each
  csum[tid] = 0.f;
  __syncthreads();

  const float* xg = x + ((size_t)b * 64 + (size_t)rg * 8) * C_ + col8;
  char* img = xbb + (size_t)b * 2 * TILE_B;
  float s0=0,s1=0,s2=0,s3=0,s4=0,s5=0,s6=0,s7=0;
#pragma unroll
  for (int j = 0; j < 8; ++j) {
    int row = rg * 8 + j;             // 0..63
    float4 a = *(const float4*)(xg + (size_t)j * C_);
    float4 c = *(const float4*)(xg + (size_t)j * C_ + 4);
    uint4 w;
    w.x = pack2(a.x, a.y); w.y = pack2(a.z, a.w);
    w.z = pack2(c.x, c.y); w.w = pack2(c.z, c.w);
    int rt = row & 31;                // row within tile
    int tl = row >> 5;                // tile 0/1
    *(uint4*)(img + tl * TILE_B + ((rt * 768 + col8 * 2) ^ ((rt & 7) << 4))) = w;
    s0 += a.x; s1 += a.y; s2 += a.z; s3 += a.w;
    s4 += c.x; s5 += c.y; s6 += c.z; s7 += c.w;
  }
  atomicAdd(&csum[col8 + 0], s0); atomicAdd(&csum[col8 + 1], s1);
  atomicAdd(&csum[col8 + 2], s2); atomicAdd(&csum[col8 + 3], s3);
  atomicAdd(&csum[col8 + 4], s4); atomicAdd(&csum[col8 + 5], s5);
  atomicAdd(&csum[col8 + 6], s6); atomicAdd(&csum[col8 + 7], s7);
  __syncthreads();
  atomicAdd(&xsum[g * C_ + tid], csum[tid]);
}

// ---------------- K1 (fallback): xsum only ----------------
__global__ __launch_bounds__(384) void k_xsum(const float* __restrict__ x,
                                              float* __restrict__ xsum) {
  __shared__ float sh[4][C_];
  const int tid = threadIdx.x;
  const int c4  = (tid % 96) * 4;
  const int rg  = tid / 96;
  const int b   = blockIdx.x;
  const int g   = b >> 3;
  const float* p = x + ((size_t)b * 128 + (size_t)rg * 32) * C_ + c4;
  f32x4 s = {0.f, 0.f, 0.f, 0.f};
#pragma unroll 8
  for (int r = 0; r < 32; ++r) {
    float4 v = *(const float4*)(p + (size_t)r * C_);
    s.x += v.x; s.y += v.y; s.z += v.z; s.w += v.w;
  }
  *(f32x4*)&sh[rg][c4] = s;
  __syncthreads();
  if (rg == 0) {
#pragma unroll
    for (int j = 0; j < 4; ++j) {
      float v = sh[0][c4 + j] + sh[1][c4 + j] + sh[2][c4 + j] + sh[3][c4 + j];
      atomicAdd(&xsum[g * C_ + c4 + j], v);
    }
  }
}

// ---------------- K2: cv[g][c] = xsum[g]@Wk[:,c] + N*bk[c] ----------------
__global__ void k_cv(const float* __restrict__ xsum, const float* __restrict__ w_qkv,
                     const float* __restrict__ b_qkv, float* __restrict__ cv) {
  __shared__ float xs[C_];
  int g = blockIdx.x, c = threadIdx.x;   // 384 threads
  xs[c] = xsum[g * C_ + c];
  __syncthreads();
  float acc = 0.f;
#pragma unroll 4
  for (int k = 0; k < C_; ++k) acc += xs[k] * w_qkv[k * QKVD + 1 + c];
  cv[g * C_ + c] = acc + (float)N_ * b_qkv[1 + c];
}

// ------- K3: pack Wv (w_qkv[:,385:769]) and Wp (w_proj) as bf16 frag-major -------
__global__ void k_pack(const float* __restrict__ w_qkv, const float* __restrict__ w_proj,
                       unsigned short* __restrict__ pWv, unsigned short* __restrict__ pWp) {
  int bid = blockIdx.x;
  int mat = bid / 288;             // 0: Wv, 1: Wp    (288 = 12 kk * 24 nf)
  int r   = bid % 288;
  int kk = r / 24, nf = r % 24;
  int lane = threadIdx.x;          // 64
  int kbase = kk * 32 + (lane >> 4) * 8;
  int n = nf * 16 + (lane & 15);
  unsigned v[4];
#pragma unroll
  for (int jj = 0; jj < 4; ++jj) {
    int k0 = kbase + jj * 2;
    float f0 = mat ? w_proj[(size_t)k0 * C_ + n]       : w_qkv[(size_t)k0 * QKVD + 385 + n];
    float f1 = mat ? w_proj[(size_t)(k0 + 1) * C_ + n] : w_qkv[(size_t)(k0 + 1) * QKVD + 385 + n];
    v[jj] = (unsigned)f2bf(f0) | ((unsigned)f2bf(f1) << 16);
  }
  unsigned short* dst = (mat ? pWp : pWv) + ((size_t)r * 64 + lane) * 8;
  uint4 w; w.x = v[0]; w.y = v[1]; w.z = v[2]; w.w = v[3];
  *(uint4*)dst = w;
}

// ---------------- K4: fused value-GEMM -> relu*cv -> proj-GEMM ----------------
// 4096 blocks x 512 thr (8 waves). Block = 32 rows x 384 cols; wave = 32r x 48c,
// acc[2][3] (r10 winner: VGPR 52). PRE: identity global_load_lds from swizzled
// bf16 image (zero staging VALU/VGPR). All register indices compile-time.
template <bool PRE>
__global__ __launch_bounds__(512) void k_fused(
    const float* __restrict__ x, const char* __restrict__ xbb,
    const unsigned short* __restrict__ pWv, const unsigned short* __restrict__ pWp,
    const float* __restrict__ cv, const float* __restrict__ b_qkv,
    const float* __restrict__ b_proj, float* __restrict__ out) {
  __shared__ __align__(16) char tile[32 * 768];   // 32 x 384 bf16, XOR-swizzled
  __shared__ float cv_l[C_], bv_l[C_], bp_l[C_];

  const int tid  = threadIdx.x;
  const int lane = tid & 63;
  const int wv   = tid >> 6;                 // 0..7
  const int R0   = blockIdx.x * 32;
  const int g    = R0 >> 10;

  if (tid < C_) {
    cv_l[tid] = cv[g * C_ + tid];
    bv_l[tid] = b_qkv[1 + C_ + tid];
    bp_l[tid] = b_proj[tid];
  }

  if constexpr (PRE) {
    // identity copy of the pre-swizzled bf16 image (async, no regs)
    const char* img = xbb + (size_t)blockIdx.x * TILE_B;
#pragma unroll
    for (int j = 0; j < 3; ++j) {
      int cb = (wv * 3 + j) * 1024;          // 8 waves x 3 x 1KB = 24 KB
      stage16(img + cb + lane * 16, tile + cb, lane);
    }
  } else {
    const float* xg = x + (size_t)R0 * C_;
#pragma unroll
    for (int j = 0; j < 3; ++j) {
      int ch  = tid + j * 512;
      int row = ch / 48;
      int c8  = (ch % 48) * 8;
      const float4* s0 = (const float4*)(xg + (size_t)row * C_ + c8);
      float4 a = s0[0], b = s0[1];
      uint4 w;
      w.x = pack2(a.x, a.y); w.y = pack2(a.z, a.w);
      w.z = pack2(b.x, b.y); w.w = pack2(b.z, b.w);
      int byte = (row * 768 + c8 * 2) ^ ((row & 7) << 4);
      *(uint4*)(tile + byte) = w;
    }
  }
  __syncthreads();

  const f32x4 zero = {0.f, 0.f, 0.f, 0.f};
  f32x4 acc[2][3];
#pragma unroll
  for (int m = 0; m < 2; ++m)
#pragma unroll
    for (int n = 0; n < 3; ++n) acc[m][n] = zero;

  // ---- GEMM1: value = x @ Wv ----
  for (int kk = 0; kk < 12; ++kk) {
    frag_t A[2], Bv[3];
    int kb2 = (kk * 32 + (lane >> 4) * 8) * 2;
#pragma unroll
    for (int m = 0; m < 2; ++m) {
      int row = m * 16 + (lane & 15);
      A[m] = *(const frag_t*)(tile + ((row * 768 + kb2) ^ ((row & 7) << 4)));
    }
    const unsigned short* bp_ = pWv + ((size_t)(kk * 24 + wv * 3) * 64 + lane) * 8;
#pragma unroll
    for (int n = 0; n < 3; ++n) Bv[n] = *(const frag_t*)(bp_ + (size_t)n * 64 * 8);
#pragma unroll
    for (int m = 0; m < 2; ++m)
#pragma unroll
      for (int n = 0; n < 3; ++n) acc[m][n] = mfma_bf16(A[m], Bv[n], acc[m][n]);
  }
  __syncthreads();   // all waves done reading x tile

  // ---- epilogue1: gated = relu(value + bv) * cv -> bf16 -> same LDS tile ----
#pragma unroll
  for (int m = 0; m < 2; ++m) {
#pragma unroll
    for (int n = 0; n < 3; ++n) {
      int col = wv * 48 + n * 16 + (lane & 15);
      float cvv = cv_l[col], bvv = bv_l[col];
#pragma unroll
      for (int r = 0; r < 4; ++r) {
        int row = m * 16 + (lane >> 4) * 4 + r;   // verified C/D layout
        float val = fmaxf(acc[m][n][r] + bvv, 0.f) * cvv;
        *(unsigned short*)(tile + ((row * 768 + col * 2) ^ ((row & 7) << 4))) = f2bf(val);
      }
    }
  }
  __syncthreads();   // gated tile complete

  // ---- GEMM2: out = gated @ Wp ----
#pragma unroll
  for (int m = 0; m < 2; ++m)
#pragma unroll
    for (int n = 0; n < 3; ++n) acc[m][n] = zero;

  for (int kk = 0; kk < 12; ++kk) {
    frag_t A[2], Bv[3];
    int kb2 = (kk * 32 + (lane >> 4) * 8) * 2;
#pragma unroll
    for (int m = 0; m < 2; ++m) {
      int row = m * 16 + (lane & 15);
      A[m] = *(const frag_t*)(tile + ((row * 768 + kb2) ^ ((row & 7) << 4)));
    }
    const unsigned short* bp_ = pWp + ((size_t)(kk * 24 + wv * 3) * 64 + lane) * 8;
#pragma unroll
    for (int n = 0; n < 3; ++n) Bv[n] = *(const frag_t*)(bp_ + (size_t)n * 64 * 8);
#pragma unroll
    for (int m = 0; m < 2; ++m)
#pragma unroll
      for (int n = 0; n < 3; ++n) acc[m][n] = mfma_bf16(A[m], Bv[n], acc[m][n]);
  }

  // ---- epilogue2: out = acc + bp ----
#pragma unroll
  for (int m = 0; m < 2; ++m) {
#pragma unroll
    for (int n = 0; n < 3; ++n) {
      int col = wv * 48 + n * 16 + (lane & 15);
      float bpv = bp_l[col];
#pragma unroll
      for (int r = 0; r < 4; ++r) {
        int row = m * 16 + (lane >> 4) * 4 + r;
        out[(size_t)(R0 + row) * C_ + col] = acc[m][n][r] + bpv;
      }
    }
  }
}

extern "C" void kernel_launch(void* const* d_in, const int* in_sizes, int n_in,
                              void* d_out, int out_size, void* d_ws, size_t ws_size,
                              hipStream_t stream) {
  const float* x      = (const float*)d_in[0];
  const float* w_qkv  = (const float*)d_in[1];
  const float* b_qkv  = (const float*)d_in[2];
  const float* w_proj = (const float*)d_in[3];
  const float* b_proj = (const float*)d_in[4];
  float* out = (float*)d_out;

  // ws: xsum | cv | pWv | pWp | xbb (4096 swizzled 24KB tile images, ~100.7 MB)
  float* xsum = (float*)d_ws;
  float* cvp  = xsum + G_ * C_;
  unsigned short* pWv = (unsigned short*)(cvp + G_ * C_);
  unsigned short* pWp = pWv + C_ * C_;
  char* xbb = (char*)(pWp + C_ * C_);

  const size_t need = 983040 + (size_t)4096 * TILE_B;   // ~101.6 MB

  hipMemsetAsync(xsum, 0, G_ * C_ * sizeof(float), stream);
  k_pack<<<576, 64, 0, stream>>>(w_qkv, w_proj, pWv, pWp);

  if (ws_size >= need) {
    k_prep<<<2048, 384, 0, stream>>>(x, xbb, xsum);
    k_cv<<<G_, C_, 0, stream>>>(xsum, w_qkv, b_qkv, cvp);
    k_fused<true><<<4096, 512, 0, stream>>>(x, xbb, pWv, pWp, cvp, b_qkv, b_proj, out);
  } else {
    k_xsum<<<1024, 384, 0, stream>>>(x, xsum);
    k_cv<<<G_, C_, 0, stream>>>(xsum, w_qkv, b_qkv, cvp);
    k_fused<false><<<4096, 512, 0, stream>>>(x, xbb, pWv, pWp, cvp, b_qkv, b_proj, out);
  }
}